// Round 6
// baseline (1423.494 us; speedup 1.0000x reference)
//
#include <hip/hip_runtime.h>
#include <cfloat>

#define N_ROWS 65536
#define DIM 256
#define K_CODES 2048

typedef float f32x2 __attribute__((ext_vector_type(2)));
typedef float f32x4 __attribute__((ext_vector_type(4)));
typedef short short8 __attribute__((ext_vector_type(8)));

// ---------------- bf16 helpers (RNE) ----------------
__device__ __forceinline__ unsigned short f2bf(float x) {
    unsigned u = __float_as_uint(x);
    u += 0x7fffu + ((u >> 16) & 1u);      // round-nearest-even
    return (unsigned short)(u >> 16);
}
__device__ __forceinline__ float bf2f(unsigned short b) {
    return __uint_as_float(((unsigned)b) << 16);
}

#define GLL16(gp, lp) \
    __builtin_amdgcn_global_load_lds((const __attribute__((address_space(1))) void*)(gp), \
                                     (__attribute__((address_space(3))) void*)(lp), 16, 0, 0)

// ---------------- e_sq precompute: one wave per code ----------------
__global__ __launch_bounds__(256)
void vq_esq_kernel(const float* __restrict__ emb, float* __restrict__ esq) {
    int w = threadIdx.x >> 6;
    int lane = threadIdx.x & 63;
    int k = blockIdx.x * 4 + w;
    float4 v = *(const float4*)&emb[(size_t)k * DIM + lane * 4];
    float s = v.x * v.x + v.y * v.y + v.z * v.z + v.w * v.w;
    #pragma unroll
    for (int off = 32; off >= 1; off >>= 1) s += __shfl_xor(s, off, 64);
    if (lane == 0) esq[k] = s;
}

// ---------------- z split (h+m) fused with z_sq (one pass over z) -------
// Each wave covers exactly one row (64 threads x 4 floats = 256).
// zsq rounding only shifts a row's distances uniformly -> argmin unaffected.
__global__ __launch_bounds__(256)
void vq_splitz_kernel(const float* __restrict__ src,
                      unsigned short* __restrict__ H,
                      unsigned short* __restrict__ M,
                      float* __restrict__ zsq_g) {
    const int tid = threadIdx.x;
    const size_t i = (size_t)blockIdx.x * 256 + tid;
    float4 v = *(const float4*)&src[4 * i];
    ushort4 h, m;
    #define SP1(c) { h.c = f2bf(v.c); float r = v.c - bf2f(h.c); m.c = f2bf(r); }
    SP1(x) SP1(y) SP1(z) SP1(w)
    #undef SP1
    *(ushort4*)&H[4 * i] = h;
    *(ushort4*)&M[4 * i] = m;
    float s = ((v.x * v.x + v.y * v.y) + v.z * v.z) + v.w * v.w;
    #pragma unroll
    for (int off = 32; off >= 1; off >>= 1) s += __shfl_xor(s, off, 64);
    if ((tid & 63) == 0) zsq_g[blockIdx.x * 4 + (tid >> 6)] = s;
}

// ---------------- emb split (h+m) ----------------
__global__ __launch_bounds__(256)
void vq_split2_kernel(const float* __restrict__ src,
                      unsigned short* __restrict__ H,
                      unsigned short* __restrict__ M) {
    const size_t i = (size_t)blockIdx.x * 256 + threadIdx.x;
    float4 v = *(const float4*)&src[4 * i];
    ushort4 h, m;
    #define SP1(c) { h.c = f2bf(v.c); float r = v.c - bf2f(h.c); m.c = f2bf(r); }
    SP1(x) SP1(y) SP1(z) SP1(w)
    #undef SP1
    *(ushort4*)&H[4 * i] = h;
    *(ushort4*)&M[4 * i] = m;
}

// ---------------- MFMA GEMM v3: A-resident LDS, B direct from L2 --------
// R6 vs R5: B is NOT staged through LDS. Eh+Em = 2 MB -> resident in every
// XCD L2; B fragments are gathered straight from global (16 rows x 64B per
// load, full cache lines). This removes ALL K-loop barriers (R5 had 64
// barrier+vmcnt(0) drains at 1 wave/SIMD = the stall) and cuts LDS to
// ~73 KB -> 2 blocks/CU (2 waves/SIMD of TLP to hide the L2 gather).
// A stage + swizzle + scoring + top-2 merge identical to verified R5.
__global__ __launch_bounds__(256, 1)
void vq_gemm_kernel(const unsigned short* __restrict__ Zh,
                    const unsigned short* __restrict__ Zm,
                    const unsigned short* __restrict__ Eh,
                    const unsigned short* __restrict__ Em,
                    const float* __restrict__ zsq_g,
                    const float* __restrict__ esq_g,
                    int* __restrict__ top2) {
    __shared__ __align__(16) unsigned short Albs[8 * 64 * 64];   // 64 KB
    __shared__ float zsq_s[64];
    __shared__ float mv[2][4][64][2];
    __shared__ int   mi[2][4][64][2];

    const int tid  = threadIdx.x;
    const int wid  = tid >> 6;
    const int lane = tid & 63;
    const int m0   = blockIdx.x * 64;
    const int rowL = lane & 15;
    const int kc   = lane >> 4;

    if (tid < 64) zsq_s[tid] = zsq_g[m0 + tid];

    // ---- persistent A stage: regions 0-3 = Zh kkb 0-3, 4-7 = Zm kkb 0-3 ----
    {
        const int slot = lane & 7;
        #pragma unroll
        for (int i = 0; i < 16; ++i) {
            const int rowlin = wid * 128 + i * 8 + (lane >> 3);  // 0..511
            const int region = rowlin >> 6;
            const int r      = rowlin & 63;
            const int c      = slot ^ (r & 7);
            const unsigned short* Ap = (region < 4) ? Zh : Zm;
            const int kkb = region & 3;
            GLL16(Ap + (size_t)(m0 + r) * DIM + kkb * 64 + c * 8,
                  (char*)Albs + wid * 16384 + i * 1024);
        }
    }
    __syncthreads();

    float b1v[16], b2v[16];
    int   b1i[16], b2i[16];
    #pragma unroll
    for (int e = 0; e < 16; ++e) {
        b1v[e] = FLT_MAX; b2v[e] = FLT_MAX;
        b1i[e] = 0x7fffffff; b2i[e] = 0x7fffffff;
    }

    #pragma unroll 1
    for (int nt = 0; nt < 8; ++nt) {
        f32x4 acc[4][4];
        #pragma unroll
        for (int mf = 0; mf < 4; ++mf)
            #pragma unroll
            for (int nf = 0; nf < 4; ++nf)
                acc[mf][nf] = (f32x4){0.f, 0.f, 0.f, 0.f};

        #pragma unroll
        for (int s = 0; s < 8; ++s) {
            const unsigned short* Bp = (s < 4) ? Eh : Em;
            const int kkb = s & 3;
            // B fragments straight from global (L2-resident plane)
            short8 bF[4][2];
            #pragma unroll
            for (int nf = 0; nf < 4; ++nf) {
                const int code = nt * 256 + wid * 64 + nf * 16 + rowL;
                const unsigned short* br = Bp + (size_t)code * DIM + kkb * 64;
                #pragma unroll
                for (int kh = 0; kh < 2; ++kh)
                    bF[nf][kh] = *(const short8*)(br + (kh * 4 + kc) * 8);
            }
            // A-plane passes: s<4 (Eh): Zh then Zm; s>=4 (Em): Zh only
            const int NPL = (s < 4) ? 2 : 1;
            #pragma unroll
            for (int pl = 0; pl < NPL; ++pl) {
                const int region = (pl == 0 ? 0 : 4) + kkb;
                short8 aF[4][2];
                #pragma unroll
                for (int mf = 0; mf < 4; ++mf)
                    #pragma unroll
                    for (int kh = 0; kh < 2; ++kh) {
                        const int r = mf * 16 + rowL;
                        const int sw = (kh * 4 + kc) ^ (r & 7);
                        aF[mf][kh] = *(const short8*)((const char*)Albs + region * 8192 + r * 128 + sw * 16);
                    }
                #pragma unroll
                for (int kh = 0; kh < 2; ++kh)
                    #pragma unroll
                    for (int mf = 0; mf < 4; ++mf)
                        #pragma unroll
                        for (int nf = 0; nf < 4; ++nf)
                            acc[mf][nf] = __builtin_amdgcn_mfma_f32_16x16x32_bf16(
                                aF[mf][kh], bF[nf][kh], acc[mf][nf], 0, 0, 0);
            }
        }

        // ---- score this nt: dist = fl(zs+es) - 2*cross, running top-2 ----
        #pragma unroll
        for (int nf = 0; nf < 4; ++nf) {
            const int code = nt * 256 + wid * 64 + nf * 16 + rowL;
            const float es = esq_g[code];
            #pragma unroll
            for (int mf = 0; mf < 4; ++mf)
                #pragma unroll
                for (int rg = 0; rg < 4; ++rg) {
                    const int e = mf * 4 + rg;
                    const float zs = zsq_s[mf * 16 + (lane >> 4) * 4 + rg];
                    float t = zs + es;
                    float dist = t - 2.0f * acc[mf][nf][rg];
                    bool better1 = (dist < b1v[e]) || (dist == b1v[e] && code < b1i[e]);
                    float ov = b1v[e]; int oi = b1i[e];
                    if (better1) { b1v[e] = dist; b1i[e] = code; }
                    float dv = better1 ? ov : dist;
                    int   di = better1 ? oi : code;
                    bool ins2 = (dv < b2v[e]) || (dv == b2v[e] && di < b2i[e]);
                    if (ins2) { b2v[e] = dv; b2i[e] = di; }
                }
        }

        // ---- half boundary: merge wave-local top2 across code columns ----
        if ((nt & 3) == 3) {
            const int h = nt >> 2;
            #pragma unroll
            for (int e = 0; e < 16; ++e) {
                #pragma unroll
                for (int off = 1; off <= 8; off <<= 1) {
                    float o1v = __shfl_xor(b1v[e], off, 64); int o1i = __shfl_xor(b1i[e], off, 64);
                    float o2v = __shfl_xor(b2v[e], off, 64); int o2i = __shfl_xor(b2i[e], off, 64);
                    bool t1 = (o1v < b1v[e]) || (o1v == b1v[e] && o1i < b1i[e]);
                    float dv = t1 ? b1v[e] : o1v; int di = t1 ? b1i[e] : o1i;
                    if (t1) { b1v[e] = o1v; b1i[e] = o1i; }
                    bool t2 = (dv < b2v[e]) || (dv == b2v[e] && di < b2i[e]);
                    if (t2) { b2v[e] = dv; b2i[e] = di; }
                    bool t3 = (o2v < b2v[e]) || (o2v == b2v[e] && o2i < b2i[e]);
                    if (t3) { b2v[e] = o2v; b2i[e] = o2i; }
                }
            }
            if ((lane & 15) == 0) {
                #pragma unroll
                for (int mf = 0; mf < 4; ++mf)
                    #pragma unroll
                    for (int rg = 0; rg < 4; ++rg) {
                        const int rl = mf * 16 + (lane >> 4) * 4 + rg;
                        const int e = mf * 4 + rg;
                        mv[h][wid][rl][0] = b1v[e]; mi[h][wid][rl][0] = b1i[e];
                        mv[h][wid][rl][1] = b2v[e]; mi[h][wid][rl][1] = b2i[e];
                    }
            }
            #pragma unroll
            for (int e = 0; e < 16; ++e) {
                b1v[e] = FLT_MAX; b2v[e] = FLT_MAX;
                b1i[e] = 0x7fffffff; b2i[e] = 0x7fffffff;
            }
        }
    }

    __syncthreads();
    // ---- final merge across the 4 waves, write top-2 per half ----
    if (tid < 128) {
        const int h = tid >> 6, r = tid & 63;
        float v1 = FLT_MAX, v2 = FLT_MAX;
        int i1 = 0x7fffffff, i2 = 0x7fffffff;
        #pragma unroll
        for (int w = 0; w < 4; ++w)
            #pragma unroll
            for (int e2 = 0; e2 < 2; ++e2) {
                float v = mv[h][w][r][e2]; int ii = mi[h][w][r][e2];
                bool t1 = (v < v1) || (v == v1 && ii < i1);
                if (t1) { v2 = v1; i2 = i1; v1 = v; i1 = ii; }
                else {
                    bool t2 = (v < v2) || (v == v2 && ii < i2);
                    if (t2) { v2 = v; i2 = ii; }
                }
            }
        top2[(m0 + r) * 4 + h * 2 + 0] = i1;
        top2[(m0 + r) * 4 + h * 2 + 1] = i2;
    }
}

// ---------------- exact rescore of 4 candidates + epilogue ----------------
// (proven in R3/R4/R5 — unchanged)
__global__ __launch_bounds__(256)
void vq_rescue_kernel(const float* __restrict__ z, const float* __restrict__ emb,
                      const float* __restrict__ zsq_g, const float* __restrict__ esq_g,
                      const int* __restrict__ top2,
                      float* __restrict__ out, float* __restrict__ loss_acc) {
    __shared__ float lred[4];
    const int tid = threadIdx.x;
    const int wid = tid >> 6, lane = tid & 63;
    const int row = blockIdx.x * 4 + wid;
    const int cand = top2[row * 4 + (lane & 3)];
    const float* zr = z + (size_t)row * DIM;
    const float* er = emb + (size_t)cand * DIM;
    float a = 0.f;
    #pragma unroll 8
    for (int d4 = 0; d4 < 64; ++d4) {
        float4 zv = *(const float4*)&zr[4 * d4];
        float4 ev = *(const float4*)&er[4 * d4];
        a = fmaf(zv.x, ev.x, a); a = fmaf(zv.y, ev.y, a);
        a = fmaf(zv.z, ev.z, a); a = fmaf(zv.w, ev.w, a);
    }
    float t = zsq_g[row] + esq_g[cand];
    float dist = t - 2.0f * a;
    int best = cand;
    #pragma unroll
    for (int off = 1; off <= 2; off <<= 1) {
        float ov = __shfl_xor(dist, off, 64);
        int   oi = __shfl_xor(best, off, 64);
        bool tk = (ov < dist) || (ov == dist && oi < best);
        dist = tk ? ov : dist; best = tk ? oi : best;
    }
    float4 q4 = *(const float4*)&emb[(size_t)best * DIM + 4 * lane];
    float4 z4 = *(const float4*)&zr[4 * lane];
    float4 o; float dx, lsum = 0.f;
    dx = q4.x - z4.x; o.x = z4.x + dx; lsum = fmaf(dx, dx, lsum);
    dx = q4.y - z4.y; o.y = z4.y + dx; lsum = fmaf(dx, dx, lsum);
    dx = q4.z - z4.z; o.z = z4.z + dx; lsum = fmaf(dx, dx, lsum);
    dx = q4.w - z4.w; o.w = z4.w + dx; lsum = fmaf(dx, dx, lsum);
    *(float4*)&out[(size_t)row * DIM + 4 * lane] = o;
    #pragma unroll
    for (int off = 32; off >= 1; off >>= 1) lsum += __shfl_xor(lsum, off, 64);
    if (lane == 0) lred[wid] = lsum;
    __syncthreads();
    if (tid == 0) atomicAdd(loss_acc, lred[0] + lred[1] + lred[2] + lred[3]);
    if (lane == 0) out[(size_t)N_ROWS * DIM + 1 + row] = (float)best;
}

// =================== legacy R2 path (fallback if ws too small) ===========
#define MT 128
#define KT 256
#define DC 16
#define BLOCK 256
#define ZSTR (MT + 4)
#define ESTR (KT + 4)
#define NSTAGES ((DIM / DC) * (K_CODES / KT))

#define LOHALF(v) __builtin_shufflevector(v, v, 0, 1)
#define HIHALF(v) __builtin_shufflevector(v, v, 2, 3)
#define PK_FMA_LO(acc, ap, bp) \
    asm("v_pk_fma_f32 %0, %1, %2, %0 op_sel:[0,0,0] op_sel_hi:[0,1,1]" \
        : "+v"(acc) : "v"(ap), "v"(bp))
#define PK_FMA_HI(acc, ap, bp) \
    asm("v_pk_fma_f32 %0, %1, %2, %0 op_sel:[1,0,0] op_sel_hi:[1,1,1]" \
        : "+v"(acc) : "v"(ap), "v"(bp))

__global__ __launch_bounds__(BLOCK, 1)
void vq_main_kernel(const float* __restrict__ z,
                    const float* __restrict__ emb,
                    const float* __restrict__ esq,
                    float* __restrict__ out,
                    float* __restrict__ loss_acc) {
    __shared__ float zS[2][DC][ZSTR];
    __shared__ float eT[2][DC][ESTR];
    __shared__ float zsq_s[MT];
    __shared__ int   best_s[MT];
    __shared__ float lred[4];

    const int tid = threadIdx.x;
    const int m0  = blockIdx.x * MT;
    const int rg  = tid >> 5;
    const int cg  = tid & 31;
    const int esr = tid >> 2;
    const int esf = tid & 3;
    const int zr  = tid >> 1;
    const int zh  = tid & 1;

    {
        const float* zp = &z[(size_t)(m0 + zr) * DIM + zh * 64];
        float sA = 0.f, sB = 0.f;
        #pragma unroll
        for (int d4 = 0; d4 < 16; ++d4) {
            float4 v = *(const float4*)&zp[d4 * 4];
            sA += v.x * v.x; sA += v.y * v.y; sA += v.z * v.z; sA += v.w * v.w;
        }
        #pragma unroll
        for (int d4 = 0; d4 < 16; ++d4) {
            float4 v = *(const float4*)&zp[128 + d4 * 4];
            sB += v.x * v.x; sB += v.y * v.y; sB += v.z * v.z; sB += v.w * v.w;
        }
        float s = sA + sB;
        s += __shfl_down(s, 1, 64);
        if (zh == 0) zsq_s[zr] = s;
    }
    {
        const float* zp = &z[(size_t)(m0 + zr) * DIM + 8 * zh];
        float4 za = *(const float4*)&zp[0];
        float4 zb = *(const float4*)&zp[4];
        zS[0][8 * zh + 0][zr] = za.x; zS[0][8 * zh + 1][zr] = za.y;
        zS[0][8 * zh + 2][zr] = za.z; zS[0][8 * zh + 3][zr] = za.w;
        zS[0][8 * zh + 4][zr] = zb.x; zS[0][8 * zh + 5][zr] = zb.y;
        zS[0][8 * zh + 6][zr] = zb.z; zS[0][8 * zh + 7][zr] = zb.w;
        #pragma unroll
        for (int cb = 0; cb < 4; ++cb) {
            int c = esr + cb * 64;
            float4 ev = *(const float4*)&emb[(size_t)c * DIM + 4 * esf];
            eT[0][4 * esf + 0][c] = ev.x; eT[0][4 * esf + 1][c] = ev.y;
            eT[0][4 * esf + 2][c] = ev.z; eT[0][4 * esf + 3][c] = ev.w;
        }
    }
    __syncthreads();

    float bestv[16];
    int   besti[16];
    #pragma unroll
    for (int j = 0; j < 16; ++j) { bestv[j] = FLT_MAX; besti[j] = 0; }

    f32x2 acc2[16][4];

    for (int s = 0; s < NSTAGES; ++s) {
        const int p     = s & 1;
        const int kt    = (s >> 4) * KT;
        const int dcIdx = s & 15;

        if (dcIdx == 0) {
            #pragma unroll
            for (int j = 0; j < 16; ++j)
                #pragma unroll
                for (int i2 = 0; i2 < 4; ++i2) acc2[j][i2] = (f32x2){0.f, 0.f};
        }

        const int sn  = (s + 1 < NSTAGES) ? s + 1 : s;
        const int nkt = (sn >> 4) * KT;
        const int ndc = (sn & 15) * DC;
        float4 zn0 = *(const float4*)&z[(size_t)(m0 + zr) * DIM + ndc + 8 * zh];
        float4 zn1 = *(const float4*)&z[(size_t)(m0 + zr) * DIM + ndc + 8 * zh + 4];
        float4 en0 = *(const float4*)&emb[(size_t)(nkt + esr +   0) * DIM + ndc + 4 * esf];
        float4 en1 = *(const float4*)&emb[(size_t)(nkt + esr +  64) * DIM + ndc + 4 * esf];
        float4 en2 = *(const float4*)&emb[(size_t)(nkt + esr + 128) * DIM + ndc + 4 * esf];
        float4 en3 = *(const float4*)&emb[(size_t)(nkt + esr + 192) * DIM + ndc + 4 * esf];

        #pragma unroll
        for (int d = 0; d < DC; ++d) {
            f32x4 a0 = *(const f32x4*)&zS[p][d][16 * rg];
            f32x4 a1 = *(const f32x4*)&zS[p][d][16 * rg + 4];
            f32x4 a2 = *(const f32x4*)&zS[p][d][16 * rg + 8];
            f32x4 a3 = *(const f32x4*)&zS[p][d][16 * rg + 12];
            f32x4 b0 = *(const f32x4*)&eT[p][d][4 * cg];
            f32x4 b1 = *(const f32x4*)&eT[p][d][128 + 4 * cg];
            f32x2 ap[8] = { LOHALF(a0), HIHALF(a0), LOHALF(a1), HIHALF(a1),
                            LOHALF(a2), HIHALF(a2), LOHALF(a3), HIHALF(a3) };
            f32x2 bp[4] = { LOHALF(b0), HIHALF(b0), LOHALF(b1), HIHALF(b1) };
            #pragma unroll
            for (int jp = 0; jp < 8; ++jp) {
                #pragma unroll
                for (int i2 = 0; i2 < 4; ++i2) {
                    PK_FMA_LO(acc2[2 * jp][i2],     ap[jp], bp[i2]);
                    PK_FMA_HI(acc2[2 * jp + 1][i2], ap[jp], bp[i2]);
                }
            }
        }
        {
            const int q = p ^ 1;
            zS[q][8 * zh + 0][zr] = zn0.x; zS[q][8 * zh + 1][zr] = zn0.y;
            zS[q][8 * zh + 2][zr] = zn0.z; zS[q][8 * zh + 3][zr] = zn0.w;
            zS[q][8 * zh + 4][zr] = zn1.x; zS[q][8 * zh + 5][zr] = zn1.y;
            zS[q][8 * zh + 6][zr] = zn1.z; zS[q][8 * zh + 7][zr] = zn1.w;
            eT[q][4 * esf + 0][esr      ] = en0.x; eT[q][4 * esf + 1][esr      ] = en0.y;
            eT[q][4 * esf + 2][esr      ] = en0.z; eT[q][4 * esf + 3][esr      ] = en0.w;
            eT[q][4 * esf + 0][esr +  64] = en1.x; eT[q][4 * esf + 1][esr +  64] = en1.y;
            eT[q][4 * esf + 2][esr +  64] = en1.z; eT[q][4 * esf + 3][esr +  64] = en1.w;
            eT[q][4 * esf + 0][esr + 128] = en2.x; eT[q][4 * esf + 1][esr + 128] = en2.y;
            eT[q][4 * esf + 2][esr + 128] = en2.z; eT[q][4 * esf + 3][esr + 128] = en2.w;
            eT[q][4 * esf + 0][esr + 192] = en3.x; eT[q][4 * esf + 1][esr + 192] = en3.y;
            eT[q][4 * esf + 2][esr + 192] = en3.z; eT[q][4 * esf + 3][esr + 192] = en3.w;
        }
        if (dcIdx == 15) {
            float4 e0 = *(const float4*)&esq[kt + 4 * cg];
            float4 e1 = *(const float4*)&esq[kt + 128 + 4 * cg];
            float es[8] = {e0.x, e0.y, e0.z, e0.w, e1.x, e1.y, e1.z, e1.w};
            #pragma unroll
            for (int j = 0; j < 16; ++j) {
                float zs = zsq_s[16 * rg + j];
                #pragma unroll
                for (int i = 0; i < 8; ++i) {
                    float aij  = acc2[j][i >> 1][i & 1];
                    float t    = zs + es[i];
                    float dist = t - 2.0f * aij;
                    int idx = (i < 4) ? (kt + 4 * cg + i) : (kt + 128 + 4 * cg + (i - 4));
                    bool better = (dist < bestv[j]);
                    bestv[j] = better ? dist : bestv[j];
                    besti[j] = better ? idx  : besti[j];
                }
            }
        }
        __syncthreads();
    }

    #pragma unroll
    for (int off = 16; off >= 1; off >>= 1) {
        #pragma unroll
        for (int j = 0; j < 16; ++j) {
            float ov = __shfl_xor(bestv[j], off, 64);
            int   oi = __shfl_xor(besti[j], off, 64);
            bool take = (ov < bestv[j]) || (ov == bestv[j] && oi < besti[j]);
            bestv[j] = take ? ov : bestv[j];
            besti[j] = take ? oi : besti[j];
        }
    }
    if (cg == 0) {
        #pragma unroll
        for (int j = 0; j < 16; ++j) best_s[16 * rg + j] = besti[j];
    }
    __syncthreads();

    float lsum = 0.f;
    const int d4 = tid & 63;
    for (int it = 0; it < 32; ++it) {
        int r  = (tid >> 6) + it * 4;
        int bk = best_s[r];
        float4 q4 = *(const float4*)&emb[(size_t)bk * DIM + 4 * d4];
        float4 z4 = *(const float4*)&z[(size_t)(m0 + r) * DIM + 4 * d4];
        float4 o;
        float dx;
        dx = q4.x - z4.x; o.x = z4.x + dx; lsum = fmaf(dx, dx, lsum);
        dx = q4.y - z4.y; o.y = z4.y + dx; lsum = fmaf(dx, dx, lsum);
        dx = q4.z - z4.z; o.z = z4.z + dx; lsum = fmaf(dx, dx, lsum);
        dx = q4.w - z4.w; o.w = z4.w + dx; lsum = fmaf(dx, dx, lsum);
        *(float4*)&out[(size_t)(m0 + r) * DIM + 4 * d4] = o;
    }
    #pragma unroll
    for (int off = 32; off >= 1; off >>= 1) lsum += __shfl_xor(lsum, off, 64);
    if ((tid & 63) == 0) lred[tid >> 6] = lsum;
    __syncthreads();
    if (tid == 0) {
        float bs = lred[0] + lred[1] + lred[2] + lred[3];
        atomicAdd(loss_acc, bs);
    }
    if (tid < MT) out[(size_t)N_ROWS * DIM + 1 + m0 + tid] = (float)best_s[tid];
}

// ---------------- finalize: vq_loss = 1.25 * mean ----------------
__global__ void vq_finalize_kernel(const float* __restrict__ loss_acc,
                                   float* __restrict__ out) {
    double s = (double)loss_acc[0];
    out[(size_t)N_ROWS * DIM] = (float)(s * 1.25 / ((double)N_ROWS * (double)DIM));
}

extern "C" void kernel_launch(void* const* d_in, const int* in_sizes, int n_in,
                              void* d_out, int out_size, void* d_ws, size_t ws_size,
                              hipStream_t stream) {
    (void)in_sizes; (void)n_in; (void)out_size;
    const float* z   = (const float*)d_in[0];
    const float* emb = (const float*)d_in[1];
    float* out = (float*)d_out;
    char* wsb = (char*)d_ws;
    float* loss_acc = (float*)wsb;              // @0
    float* esq      = (float*)(wsb + 1024);     // 2048 f

    hipMemsetAsync(d_ws, 0, sizeof(float), stream);
    vq_esq_kernel<<<K_CODES / 4, 256, 0, stream>>>(emb, esq);

    const size_t NEED = (size_t)72 << 20;       // Zh/Zm end at 72 MiB
    if (ws_size >= NEED) {
        float* zsq_g = (float*)(wsb + 16384);              // 65536 f
        int*   top2  = (int*)(wsb + ((size_t)1 << 19));    // 65536*4 int
        unsigned short* Eh = (unsigned short*)(wsb + ((size_t)2 << 20));
        unsigned short* Em = (unsigned short*)(wsb + ((size_t)3 << 20));
        unsigned short* Zh = (unsigned short*)(wsb + ((size_t)8 << 20));
        unsigned short* Zm = (unsigned short*)(wsb + ((size_t)40 << 20));
        vq_splitz_kernel<<<(N_ROWS * DIM) / 1024, 256, 0, stream>>>(z, Zh, Zm, zsq_g);
        vq_split2_kernel<<<(K_CODES * DIM) / 1024, 256, 0, stream>>>(emb, Eh, Em);
        vq_gemm_kernel<<<N_ROWS / 64, 256, 0, stream>>>(Zh, Zm, Eh, Em,
                                                        zsq_g, esq, top2);
        vq_rescue_kernel<<<N_ROWS / 4, 256, 0, stream>>>(z, emb, zsq_g, esq, top2,
                                                         out, loss_acc);
    } else {
        vq_main_kernel<<<N_ROWS / MT, BLOCK, 0, stream>>>(z, emb, esq, out, loss_acc);
    }
    vq_finalize_kernel<<<1, 1, 0, stream>>>(loss_acc, out);
}

// Round 7
// 1057.050 us; speedup vs baseline: 1.3467x; 1.3467x over previous
//
#include <hip/hip_runtime.h>
#include <cfloat>

#define N_ROWS 65536
#define DIM 256
#define K_CODES 2048

typedef float f32x2 __attribute__((ext_vector_type(2)));
typedef float f32x4 __attribute__((ext_vector_type(4)));
typedef short short8 __attribute__((ext_vector_type(8)));

// ---------------- bf16 helpers (RNE) ----------------
__device__ __forceinline__ unsigned short f2bf(float x) {
    unsigned u = __float_as_uint(x);
    u += 0x7fffu + ((u >> 16) & 1u);      // round-nearest-even
    return (unsigned short)(u >> 16);
}
__device__ __forceinline__ float bf2f(unsigned short b) {
    return __uint_as_float(((unsigned)b) << 16);
}

#define GLL16(gp, lp) \
    __builtin_amdgcn_global_load_lds((const __attribute__((address_space(1))) void*)(gp), \
                                     (__attribute__((address_space(3))) void*)(lp), 16, 0, 0)

// ---------------- e_sq precompute: one wave per code ----------------
__global__ __launch_bounds__(256)
void vq_esq_kernel(const float* __restrict__ emb, float* __restrict__ esq) {
    int w = threadIdx.x >> 6;
    int lane = threadIdx.x & 63;
    int k = blockIdx.x * 4 + w;
    float4 v = *(const float4*)&emb[(size_t)k * DIM + lane * 4];
    float s = v.x * v.x + v.y * v.y + v.z * v.z + v.w * v.w;
    #pragma unroll
    for (int off = 32; off >= 1; off >>= 1) s += __shfl_xor(s, off, 64);
    if (lane == 0) esq[k] = s;
}

// ---------------- z split (h+m) fused with z_sq (one pass over z) -------
__global__ __launch_bounds__(256)
void vq_splitz_kernel(const float* __restrict__ src,
                      unsigned short* __restrict__ H,
                      unsigned short* __restrict__ M,
                      float* __restrict__ zsq_g) {
    const int tid = threadIdx.x;
    const size_t i = (size_t)blockIdx.x * 256 + tid;
    float4 v = *(const float4*)&src[4 * i];
    ushort4 h, m;
    #define SP1(c) { h.c = f2bf(v.c); float r = v.c - bf2f(h.c); m.c = f2bf(r); }
    SP1(x) SP1(y) SP1(z) SP1(w)
    #undef SP1
    *(ushort4*)&H[4 * i] = h;
    *(ushort4*)&M[4 * i] = m;
    float s = ((v.x * v.x + v.y * v.y) + v.z * v.z) + v.w * v.w;
    #pragma unroll
    for (int off = 32; off >= 1; off >>= 1) s += __shfl_xor(s, off, 64);
    if ((tid & 63) == 0) zsq_g[blockIdx.x * 4 + (tid >> 6)] = s;
}

// ---------------- emb split (h+m) ----------------
__global__ __launch_bounds__(256)
void vq_split2_kernel(const float* __restrict__ src,
                      unsigned short* __restrict__ H,
                      unsigned short* __restrict__ M) {
    const size_t i = (size_t)blockIdx.x * 256 + threadIdx.x;
    float4 v = *(const float4*)&src[4 * i];
    ushort4 h, m;
    #define SP1(c) { h.c = f2bf(v.c); float r = v.c - bf2f(h.c); m.c = f2bf(r); }
    SP1(x) SP1(y) SP1(z) SP1(w)
    #undef SP1
    *(ushort4*)&H[4 * i] = h;
    *(ushort4*)&M[4 * i] = m;
}

// ---------------- MFMA GEMM v4: R5 dataflow, 8-wave block ----------------
// R7 vs R5: 512 threads (8 waves) instead of 256 (4). Same 64-row block,
// same A-resident LDS (Zh+Zm, 64 KB, staged once), same B dbuf (2x32 KB,
// GLL16), same swizzle & barriers. Each wave owns a 32-row x 64-code
// sub-tile (wm = wid>>2 row half, wn = wid&3 code quarter): acc 2x4 frags
// (32 VGPR), top-2 state 32 VGPR -> no spill (R6's failure), and the CU
// now runs 2 waves/SIMD so ds_read->MFMA latency and barrier drains
// interleave across waves (R5 ran 1 wave/SIMD = unhidable bubbles).
__global__ __launch_bounds__(512, 2)
void vq_gemm_kernel(const unsigned short* __restrict__ Zh,
                    const unsigned short* __restrict__ Zm,
                    const unsigned short* __restrict__ Eh,
                    const unsigned short* __restrict__ Em,
                    const float* __restrict__ zsq_g,
                    const float* __restrict__ esq_g,
                    int* __restrict__ top2) {
    __shared__ __align__(16) unsigned short Albs[8 * 64 * 64];   // 64 KB
    __shared__ __align__(16) unsigned short Bbuf[2 * 256 * 64];  // 64 KB
    __shared__ float zsq_s[64];
    __shared__ float mvv[2][4][64][2];
    __shared__ int   mii[2][4][64][2];

    const int tid  = threadIdx.x;
    const int wid  = tid >> 6;        // 0..7
    const int lane = tid & 63;
    const int m0   = blockIdx.x * 64;
    const int rowL = lane & 15;
    const int kc   = lane >> 4;       // 0..3
    const int wm   = wid >> 2;        // row half: rows 32*wm..32*wm+31
    const int wn   = wid & 3;         // code quarter within a 256-code tile

    if (tid < 64) zsq_s[tid] = zsq_g[m0 + tid];

    // ---- persistent A stage: regions 0-3 = Zh kkb 0-3, 4-7 = Zm kkb 0-3 ----
    {
        const int slot = lane & 7;
        #pragma unroll
        for (int i = 0; i < 8; ++i) {
            const int rowlin = wid * 64 + i * 8 + (lane >> 3);   // 0..511
            const int region = rowlin >> 6;
            const int r      = rowlin & 63;
            const int c      = slot ^ (r & 7);
            const unsigned short* Ap = (region < 4) ? Zh : Zm;
            const int kkb = region & 3;
            GLL16(Ap + (size_t)(m0 + r) * DIM + kkb * 64 + c * 8,
                  (char*)Albs + wid * 8192 + i * 1024);
        }
    }

    // ---- B tile stage: 256 codes x 64 d (32 KB); 4 GLL16 per thread ----
    auto stage_b = [&](int nt_, int s_, int buf_) {
        const unsigned short* Bp = (s_ < 4) ? Eh : Em;
        const int kkb  = s_ & 3;
        const int slot = lane & 7;
        #pragma unroll
        for (int i = 0; i < 4; ++i) {
            const int chunk = wid * 4 + i;                       // 0..31
            const int codelin = chunk * 8 + (lane >> 3);         // 0..255
            const int c = slot ^ (codelin & 7);
            GLL16(Bp + (size_t)(nt_ * 256 + codelin) * DIM + kkb * 64 + c * 8,
                  (char*)Bbuf + buf_ * 32768 + chunk * 1024);
        }
    };

    stage_b(0, 0, 0);
    __syncthreads();

    float b1v[8], b2v[8];
    int   b1i[8], b2i[8];
    #pragma unroll
    for (int e = 0; e < 8; ++e) {
        b1v[e] = FLT_MAX; b2v[e] = FLT_MAX;
        b1i[e] = 0x7fffffff; b2i[e] = 0x7fffffff;
    }

    #pragma unroll 1
    for (int nt = 0; nt < 8; ++nt) {
        f32x4 acc[2][4];
        #pragma unroll
        for (int mf = 0; mf < 2; ++mf)
            #pragma unroll
            for (int nf = 0; nf < 4; ++nf)
                acc[mf][nf] = (f32x4){0.f, 0.f, 0.f, 0.f};

        #pragma unroll
        for (int s = 0; s < 8; ++s) {
            const int cb = s & 1;
            // prefetch next step into the other buffer
            {
                const int sn  = (s + 1) & 7;
                const int ntn = (s == 7) ? nt + 1 : nt;
                if (ntn < 8) stage_b(ntn, sn, cb ^ 1);
            }
            const int kkb = s & 3;
            // B fragments (LDS): codes wn*64 .. wn*64+63 of this tile
            short8 bF[4][2];
            #pragma unroll
            for (int nf = 0; nf < 4; ++nf) {
                const int ct = wn * 64 + nf * 16 + rowL;         // 0..255
                #pragma unroll
                for (int kh = 0; kh < 2; ++kh) {
                    const int sw = (kh * 4 + kc) ^ (ct & 7);
                    bF[nf][kh] = *(const short8*)((const char*)Bbuf + cb * 32768 + ct * 128 + sw * 16);
                }
            }
            // A-plane passes: s<4 (Eh): Zh then Zm; s>=4 (Em): Zh only
            const int NPL = (s < 4) ? 2 : 1;
            #pragma unroll
            for (int pl = 0; pl < NPL; ++pl) {
                const int region = (pl == 0 ? 0 : 4) + kkb;
                short8 aF[2][2];
                #pragma unroll
                for (int mf = 0; mf < 2; ++mf)
                    #pragma unroll
                    for (int kh = 0; kh < 2; ++kh) {
                        const int r = wm * 32 + mf * 16 + rowL;  // 0..63
                        const int sw = (kh * 4 + kc) ^ (r & 7);
                        aF[mf][kh] = *(const short8*)((const char*)Albs + region * 8192 + r * 128 + sw * 16);
                    }
                #pragma unroll
                for (int kh = 0; kh < 2; ++kh)
                    #pragma unroll
                    for (int mf = 0; mf < 2; ++mf)
                        #pragma unroll
                        for (int nf = 0; nf < 4; ++nf)
                            acc[mf][nf] = __builtin_amdgcn_mfma_f32_16x16x32_bf16(
                                aF[mf][kh], bF[nf][kh], acc[mf][nf], 0, 0, 0);
            }
            __syncthreads();
        }

        // ---- score this nt: dist = fl(zs+es) - 2*cross, running top-2 ----
        #pragma unroll
        for (int nf = 0; nf < 4; ++nf) {
            const int code = nt * 256 + wn * 64 + nf * 16 + rowL;
            const float es = esq_g[code];
            #pragma unroll
            for (int mf = 0; mf < 2; ++mf)
                #pragma unroll
                for (int rg = 0; rg < 4; ++rg) {
                    const int e = mf * 4 + rg;
                    const float zs = zsq_s[wm * 32 + mf * 16 + kc * 4 + rg];
                    float t = zs + es;
                    float dist = t - 2.0f * acc[mf][nf][rg];
                    bool better1 = (dist < b1v[e]) || (dist == b1v[e] && code < b1i[e]);
                    float ov = b1v[e]; int oi = b1i[e];
                    if (better1) { b1v[e] = dist; b1i[e] = code; }
                    float dv = better1 ? ov : dist;
                    int   di = better1 ? oi : code;
                    bool ins2 = (dv < b2v[e]) || (dv == b2v[e] && di < b2i[e]);
                    if (ins2) { b2v[e] = dv; b2i[e] = di; }
                }
        }

        // ---- half boundary (nt 3 / 7): merge wave-local top2 across cols ----
        if ((nt & 3) == 3) {
            const int h = nt >> 2;
            #pragma unroll
            for (int e = 0; e < 8; ++e) {
                #pragma unroll
                for (int off = 1; off <= 8; off <<= 1) {
                    float o1v = __shfl_xor(b1v[e], off, 64); int o1i = __shfl_xor(b1i[e], off, 64);
                    float o2v = __shfl_xor(b2v[e], off, 64); int o2i = __shfl_xor(b2i[e], off, 64);
                    bool t1 = (o1v < b1v[e]) || (o1v == b1v[e] && o1i < b1i[e]);
                    float dv = t1 ? b1v[e] : o1v; int di = t1 ? b1i[e] : o1i;
                    if (t1) { b1v[e] = o1v; b1i[e] = o1i; }
                    bool t2 = (dv < b2v[e]) || (dv == b2v[e] && di < b2i[e]);
                    if (t2) { b2v[e] = dv; b2i[e] = di; }
                    bool t3 = (o2v < b2v[e]) || (o2v == b2v[e] && o2i < b2i[e]);
                    if (t3) { b2v[e] = o2v; b2i[e] = o2i; }
                }
            }
            if ((lane & 15) == 0) {
                #pragma unroll
                for (int mf = 0; mf < 2; ++mf)
                    #pragma unroll
                    for (int rg = 0; rg < 4; ++rg) {
                        const int rl = wm * 32 + mf * 16 + kc * 4 + rg;
                        const int e = mf * 4 + rg;
                        mvv[h][wn][rl][0] = b1v[e]; mii[h][wn][rl][0] = b1i[e];
                        mvv[h][wn][rl][1] = b2v[e]; mii[h][wn][rl][1] = b2i[e];
                    }
            }
            #pragma unroll
            for (int e = 0; e < 8; ++e) {
                b1v[e] = FLT_MAX; b2v[e] = FLT_MAX;
                b1i[e] = 0x7fffffff; b2i[e] = 0x7fffffff;
            }
        }
    }

    __syncthreads();
    // ---- final merge across the 4 code-quarters, write top-2 per half ----
    if (tid < 128) {
        const int h = tid >> 6, r = tid & 63;
        float v1 = FLT_MAX, v2 = FLT_MAX;
        int i1 = 0x7fffffff, i2 = 0x7fffffff;
        #pragma unroll
        for (int w = 0; w < 4; ++w)
            #pragma unroll
            for (int e2 = 0; e2 < 2; ++e2) {
                float v = mvv[h][w][r][e2]; int ii = mii[h][w][r][e2];
                bool t1 = (v < v1) || (v == v1 && ii < i1);
                if (t1) { v2 = v1; i2 = i1; v1 = v; i1 = ii; }
                else {
                    bool t2 = (v < v2) || (v == v2 && ii < i2);
                    if (t2) { v2 = v; i2 = ii; }
                }
            }
        top2[(m0 + r) * 4 + h * 2 + 0] = i1;
        top2[(m0 + r) * 4 + h * 2 + 1] = i2;
    }
}

// ---------------- exact rescore of 4 candidates + epilogue ----------------
// (proven in R3..R6 — unchanged)
__global__ __launch_bounds__(256)
void vq_rescue_kernel(const float* __restrict__ z, const float* __restrict__ emb,
                      const float* __restrict__ zsq_g, const float* __restrict__ esq_g,
                      const int* __restrict__ top2,
                      float* __restrict__ out, float* __restrict__ loss_acc) {
    __shared__ float lred[4];
    const int tid = threadIdx.x;
    const int wid = tid >> 6, lane = tid & 63;
    const int row = blockIdx.x * 4 + wid;
    const int cand = top2[row * 4 + (lane & 3)];
    const float* zr = z + (size_t)row * DIM;
    const float* er = emb + (size_t)cand * DIM;
    float a = 0.f;
    #pragma unroll 8
    for (int d4 = 0; d4 < 64; ++d4) {
        float4 zv = *(const float4*)&zr[4 * d4];
        float4 ev = *(const float4*)&er[4 * d4];
        a = fmaf(zv.x, ev.x, a); a = fmaf(zv.y, ev.y, a);
        a = fmaf(zv.z, ev.z, a); a = fmaf(zv.w, ev.w, a);
    }
    float t = zsq_g[row] + esq_g[cand];
    float dist = t - 2.0f * a;
    int best = cand;
    #pragma unroll
    for (int off = 1; off <= 2; off <<= 1) {
        float ov = __shfl_xor(dist, off, 64);
        int   oi = __shfl_xor(best, off, 64);
        bool tk = (ov < dist) || (ov == dist && oi < best);
        dist = tk ? ov : dist; best = tk ? oi : best;
    }
    float4 q4 = *(const float4*)&emb[(size_t)best * DIM + 4 * lane];
    float4 z4 = *(const float4*)&zr[4 * lane];
    float4 o; float dx, lsum = 0.f;
    dx = q4.x - z4.x; o.x = z4.x + dx; lsum = fmaf(dx, dx, lsum);
    dx = q4.y - z4.y; o.y = z4.y + dx; lsum = fmaf(dx, dx, lsum);
    dx = q4.z - z4.z; o.z = z4.z + dx; lsum = fmaf(dx, dx, lsum);
    dx = q4.w - z4.w; o.w = z4.w + dx; lsum = fmaf(dx, dx, lsum);
    *(float4*)&out[(size_t)row * DIM + 4 * lane] = o;
    #pragma unroll
    for (int off = 32; off >= 1; off >>= 1) lsum += __shfl_xor(lsum, off, 64);
    if (lane == 0) lred[wid] = lsum;
    __syncthreads();
    if (tid == 0) atomicAdd(loss_acc, lred[0] + lred[1] + lred[2] + lred[3]);
    if (lane == 0) out[(size_t)N_ROWS * DIM + 1 + row] = (float)best;
}

// =================== legacy R2 path (fallback if ws too small) ===========
#define MT 128
#define KT 256
#define DC 16
#define BLOCK 256
#define ZSTR (MT + 4)
#define ESTR (KT + 4)
#define NSTAGES ((DIM / DC) * (K_CODES / KT))

#define LOHALF(v) __builtin_shufflevector(v, v, 0, 1)
#define HIHALF(v) __builtin_shufflevector(v, v, 2, 3)
#define PK_FMA_LO(acc, ap, bp) \
    asm("v_pk_fma_f32 %0, %1, %2, %0 op_sel:[0,0,0] op_sel_hi:[0,1,1]" \
        : "+v"(acc) : "v"(ap), "v"(bp))
#define PK_FMA_HI(acc, ap, bp) \
    asm("v_pk_fma_f32 %0, %1, %2, %0 op_sel:[1,0,0] op_sel_hi:[1,1,1]" \
        : "+v"(acc) : "v"(ap), "v"(bp))

__global__ __launch_bounds__(BLOCK, 1)
void vq_main_kernel(const float* __restrict__ z,
                    const float* __restrict__ emb,
                    const float* __restrict__ esq,
                    float* __restrict__ out,
                    float* __restrict__ loss_acc) {
    __shared__ float zS[2][DC][ZSTR];
    __shared__ float eT[2][DC][ESTR];
    __shared__ float zsq_s[MT];
    __shared__ int   best_s[MT];
    __shared__ float lred[4];

    const int tid = threadIdx.x;
    const int m0  = blockIdx.x * MT;
    const int rg  = tid >> 5;
    const int cg  = tid & 31;
    const int esr = tid >> 2;
    const int esf = tid & 3;
    const int zr  = tid >> 1;
    const int zh  = tid & 1;

    {
        const float* zp = &z[(size_t)(m0 + zr) * DIM + zh * 64];
        float sA = 0.f, sB = 0.f;
        #pragma unroll
        for (int d4 = 0; d4 < 16; ++d4) {
            float4 v = *(const float4*)&zp[d4 * 4];
            sA += v.x * v.x; sA += v.y * v.y; sA += v.z * v.z; sA += v.w * v.w;
        }
        #pragma unroll
        for (int d4 = 0; d4 < 16; ++d4) {
            float4 v = *(const float4*)&zp[128 + d4 * 4];
            sB += v.x * v.x; sB += v.y * v.y; sB += v.z * v.z; sB += v.w * v.w;
        }
        float s = sA + sB;
        s += __shfl_down(s, 1, 64);
        if (zh == 0) zsq_s[zr] = s;
    }
    {
        const float* zp = &z[(size_t)(m0 + zr) * DIM + 8 * zh];
        float4 za = *(const float4*)&zp[0];
        float4 zb = *(const float4*)&zp[4];
        zS[0][8 * zh + 0][zr] = za.x; zS[0][8 * zh + 1][zr] = za.y;
        zS[0][8 * zh + 2][zr] = za.z; zS[0][8 * zh + 3][zr] = za.w;
        zS[0][8 * zh + 4][zr] = zb.x; zS[0][8 * zh + 5][zr] = zb.y;
        zS[0][8 * zh + 6][zr] = zb.z; zS[0][8 * zh + 7][zr] = zb.w;
        #pragma unroll
        for (int cb = 0; cb < 4; ++cb) {
            int c = esr + cb * 64;
            float4 ev = *(const float4*)&emb[(size_t)c * DIM + 4 * esf];
            eT[0][4 * esf + 0][c] = ev.x; eT[0][4 * esf + 1][c] = ev.y;
            eT[0][4 * esf + 2][c] = ev.z; eT[0][4 * esf + 3][c] = ev.w;
        }
    }
    __syncthreads();

    float bestv[16];
    int   besti[16];
    #pragma unroll
    for (int j = 0; j < 16; ++j) { bestv[j] = FLT_MAX; besti[j] = 0; }

    f32x2 acc2[16][4];

    for (int s = 0; s < NSTAGES; ++s) {
        const int p     = s & 1;
        const int kt    = (s >> 4) * KT;
        const int dcIdx = s & 15;

        if (dcIdx == 0) {
            #pragma unroll
            for (int j = 0; j < 16; ++j)
                #pragma unroll
                for (int i2 = 0; i2 < 4; ++i2) acc2[j][i2] = (f32x2){0.f, 0.f};
        }

        const int sn  = (s + 1 < NSTAGES) ? s + 1 : s;
        const int nkt = (sn >> 4) * KT;
        const int ndc = (sn & 15) * DC;
        float4 zn0 = *(const float4*)&z[(size_t)(m0 + zr) * DIM + ndc + 8 * zh];
        float4 zn1 = *(const float4*)&z[(size_t)(m0 + zr) * DIM + ndc + 8 * zh + 4];
        float4 en0 = *(const float4*)&emb[(size_t)(nkt + esr +   0) * DIM + ndc + 4 * esf];
        float4 en1 = *(const float4*)&emb[(size_t)(nkt + esr +  64) * DIM + ndc + 4 * esf];
        float4 en2 = *(const float4*)&emb[(size_t)(nkt + esr + 128) * DIM + ndc + 4 * esf];
        float4 en3 = *(const float4*)&emb[(size_t)(nkt + esr + 192) * DIM + ndc + 4 * esf];

        #pragma unroll
        for (int d = 0; d < DC; ++d) {
            f32x4 a0 = *(const f32x4*)&zS[p][d][16 * rg];
            f32x4 a1 = *(const f32x4*)&zS[p][d][16 * rg + 4];
            f32x4 a2 = *(const f32x4*)&zS[p][d][16 * rg + 8];
            f32x4 a3 = *(const f32x4*)&zS[p][d][16 * rg + 12];
            f32x4 b0 = *(const f32x4*)&eT[p][d][4 * cg];
            f32x4 b1 = *(const f32x4*)&eT[p][d][128 + 4 * cg];
            f32x2 ap[8] = { LOHALF(a0), HIHALF(a0), LOHALF(a1), HIHALF(a1),
                            LOHALF(a2), HIHALF(a2), LOHALF(a3), HIHALF(a3) };
            f32x2 bp[4] = { LOHALF(b0), HIHALF(b0), LOHALF(b1), HIHALF(b1) };
            #pragma unroll
            for (int jp = 0; jp < 8; ++jp) {
                #pragma unroll
                for (int i2 = 0; i2 < 4; ++i2) {
                    PK_FMA_LO(acc2[2 * jp][i2],     ap[jp], bp[i2]);
                    PK_FMA_HI(acc2[2 * jp + 1][i2], ap[jp], bp[i2]);
                }
            }
        }
        {
            const int q = p ^ 1;
            zS[q][8 * zh + 0][zr] = zn0.x; zS[q][8 * zh + 1][zr] = zn0.y;
            zS[q][8 * zh + 2][zr] = zn0.z; zS[q][8 * zh + 3][zr] = zn0.w;
            zS[q][8 * zh + 4][zr] = zn1.x; zS[q][8 * zh + 5][zr] = zn1.y;
            zS[q][8 * zh + 6][zr] = zn1.z; zS[q][8 * zh + 7][zr] = zn1.w;
            eT[q][4 * esf + 0][esr      ] = en0.x; eT[q][4 * esf + 1][esr      ] = en0.y;
            eT[q][4 * esf + 2][esr      ] = en0.z; eT[q][4 * esf + 3][esr      ] = en0.w;
            eT[q][4 * esf + 0][esr +  64] = en1.x; eT[q][4 * esf + 1][esr +  64] = en1.y;
            eT[q][4 * esf + 2][esr +  64] = en1.z; eT[q][4 * esf + 3][esr +  64] = en1.w;
            eT[q][4 * esf + 0][esr + 128] = en2.x; eT[q][4 * esf + 1][esr + 128] = en2.y;
            eT[q][4 * esf + 2][esr + 128] = en2.z; eT[q][4 * esf + 3][esr + 128] = en2.w;
            eT[q][4 * esf + 0][esr + 192] = en3.x; eT[q][4 * esf + 1][esr + 192] = en3.y;
            eT[q][4 * esf + 2][esr + 192] = en3.z; eT[q][4 * esf + 3][esr + 192] = en3.w;
        }
        if (dcIdx == 15) {
            float4 e0 = *(const float4*)&esq[kt + 4 * cg];
            float4 e1 = *(const float4*)&esq[kt + 128 + 4 * cg];
            float es[8] = {e0.x, e0.y, e0.z, e0.w, e1.x, e1.y, e1.z, e1.w};
            #pragma unroll
            for (int j = 0; j < 16; ++j) {
                float zs = zsq_s[16 * rg + j];
                #pragma unroll
                for (int i = 0; i < 8; ++i) {
                    float aij  = acc2[j][i >> 1][i & 1];
                    float t    = zs + es[i];
                    float dist = t - 2.0f * aij;
                    int idx = (i < 4) ? (kt + 4 * cg + i) : (kt + 128 + 4 * cg + (i - 4));
                    bool better = (dist < bestv[j]);
                    bestv[j] = better ? dist : bestv[j];
                    besti[j] = better ? idx  : besti[j];
                }
            }
        }
        __syncthreads();
    }

    #pragma unroll
    for (int off = 16; off >= 1; off >>= 1) {
        #pragma unroll
        for (int j = 0; j < 16; ++j) {
            float ov = __shfl_xor(bestv[j], off, 64);
            int   oi = __shfl_xor(besti[j], off, 64);
            bool take = (ov < bestv[j]) || (ov == bestv[j] && oi < besti[j]);
            bestv[j] = take ? ov : bestv[j];
            besti[j] = take ? oi : besti[j];
        }
    }
    if (cg == 0) {
        #pragma unroll
        for (int j = 0; j < 16; ++j) best_s[16 * rg + j] = besti[j];
    }
    __syncthreads();

    float lsum = 0.f;
    const int d4 = tid & 63;
    for (int it = 0; it < 32; ++it) {
        int r  = (tid >> 6) + it * 4;
        int bk = best_s[r];
        float4 q4 = *(const float4*)&emb[(size_t)bk * DIM + 4 * d4];
        float4 z4 = *(const float4*)&z[(size_t)(m0 + r) * DIM + 4 * d4];
        float4 o;
        float dx;
        dx = q4.x - z4.x; o.x = z4.x + dx; lsum = fmaf(dx, dx, lsum);
        dx = q4.y - z4.y; o.y = z4.y + dx; lsum = fmaf(dx, dx, lsum);
        dx = q4.z - z4.z; o.z = z4.z + dx; lsum = fmaf(dx, dx, lsum);
        dx = q4.w - z4.w; o.w = z4.w + dx; lsum = fmaf(dx, dx, lsum);
        *(float4*)&out[(size_t)(m0 + r) * DIM + 4 * d4] = o;
    }
    #pragma unroll
    for (int off = 32; off >= 1; off >>= 1) lsum += __shfl_xor(lsum, off, 64);
    if ((tid & 63) == 0) lred[tid >> 6] = lsum;
    __syncthreads();
    if (tid == 0) {
        float bs = lred[0] + lred[1] + lred[2] + lred[3];
        atomicAdd(loss_acc, bs);
    }
    if (tid < MT) out[(size_t)N_ROWS * DIM + 1 + m0 + tid] = (float)best_s[tid];
}

// ---------------- finalize: vq_loss = 1.25 * mean ----------------
__global__ void vq_finalize_kernel(const float* __restrict__ loss_acc,
                                   float* __restrict__ out) {
    double s = (double)loss_acc[0];
    out[(size_t)N_ROWS * DIM] = (float)(s * 1.25 / ((double)N_ROWS * (double)DIM));
}

extern "C" void kernel_launch(void* const* d_in, const int* in_sizes, int n_in,
                              void* d_out, int out_size, void* d_ws, size_t ws_size,
                              hipStream_t stream) {
    (void)in_sizes; (void)n_in; (void)out_size;
    const float* z   = (const float*)d_in[0];
    const float* emb = (const float*)d_in[1];
    float* out = (float*)d_out;
    char* wsb = (char*)d_ws;
    float* loss_acc = (float*)wsb;              // @0
    float* esq      = (float*)(wsb + 1024);     // 2048 f

    hipMemsetAsync(d_ws, 0, sizeof(float), stream);
    vq_esq_kernel<<<K_CODES / 4, 256, 0, stream>>>(emb, esq);

    const size_t NEED = (size_t)72 << 20;       // Zh/Zm end at 72 MiB
    if (ws_size >= NEED) {
        float* zsq_g = (float*)(wsb + 16384);              // 65536 f
        int*   top2  = (int*)(wsb + ((size_t)1 << 19));    // 65536*4 int
        unsigned short* Eh = (unsigned short*)(wsb + ((size_t)2 << 20));
        unsigned short* Em = (unsigned short*)(wsb + ((size_t)3 << 20));
        unsigned short* Zh = (unsigned short*)(wsb + ((size_t)8 << 20));
        unsigned short* Zm = (unsigned short*)(wsb + ((size_t)40 << 20));
        vq_splitz_kernel<<<(N_ROWS * DIM) / 1024, 256, 0, stream>>>(z, Zh, Zm, zsq_g);
        vq_split2_kernel<<<(K_CODES * DIM) / 1024, 256, 0, stream>>>(emb, Eh, Em);
        vq_gemm_kernel<<<N_ROWS / 64, 512, 0, stream>>>(Zh, Zm, Eh, Em,
                                                        zsq_g, esq, top2);
        vq_rescue_kernel<<<N_ROWS / 4, 256, 0, stream>>>(z, emb, zsq_g, esq, top2,
                                                         out, loss_acc);
    } else {
        vq_main_kernel<<<N_ROWS / MT, BLOCK, 0, stream>>>(z, emb, esq, out, loss_acc);
    }
    vq_finalize_kernel<<<1, 1, 0, stream>>>(loss_acc, out);
}

// Round 9
// 712.114 us; speedup vs baseline: 1.9990x; 1.4844x over previous
//
#include <hip/hip_runtime.h>
#include <cfloat>

#define N_ROWS 65536
#define DIM 256
#define K_CODES 2048

typedef float f32x2 __attribute__((ext_vector_type(2)));
typedef float f32x4 __attribute__((ext_vector_type(4)));
typedef short short8 __attribute__((ext_vector_type(8)));

// ---------------- bf16 helpers (RNE) ----------------
__device__ __forceinline__ unsigned short f2bf(float x) {
    unsigned u = __float_as_uint(x);
    u += 0x7fffu + ((u >> 16) & 1u);      // round-nearest-even
    return (unsigned short)(u >> 16);
}
__device__ __forceinline__ float bf2f(unsigned short b) {
    return __uint_as_float(((unsigned)b) << 16);
}

#define GLL16(gp, lp) \
    __builtin_amdgcn_global_load_lds((const __attribute__((address_space(1))) void*)(gp), \
                                     (__attribute__((address_space(3))) void*)(lp), 16, 0, 0)

// ---------------- e_sq precompute: one wave per code ----------------
__global__ __launch_bounds__(256)
void vq_esq_kernel(const float* __restrict__ emb, float* __restrict__ esq) {
    int w = threadIdx.x >> 6;
    int lane = threadIdx.x & 63;
    int k = blockIdx.x * 4 + w;
    float4 v = *(const float4*)&emb[(size_t)k * DIM + lane * 4];
    float s = v.x * v.x + v.y * v.y + v.z * v.z + v.w * v.w;
    #pragma unroll
    for (int off = 32; off >= 1; off >>= 1) s += __shfl_xor(s, off, 64);
    if (lane == 0) esq[k] = s;
}

// ---------------- z split (h+m) fused with z_sq (one pass over z) -------
__global__ __launch_bounds__(256)
void vq_splitz_kernel(const float* __restrict__ src,
                      unsigned short* __restrict__ H,
                      unsigned short* __restrict__ M,
                      float* __restrict__ zsq_g) {
    const int tid = threadIdx.x;
    const size_t i = (size_t)blockIdx.x * 256 + tid;
    float4 v = *(const float4*)&src[4 * i];
    ushort4 h, m;
    #define SP1(c) { h.c = f2bf(v.c); float r = v.c - bf2f(h.c); m.c = f2bf(r); }
    SP1(x) SP1(y) SP1(z) SP1(w)
    #undef SP1
    *(ushort4*)&H[4 * i] = h;
    *(ushort4*)&M[4 * i] = m;
    float s = ((v.x * v.x + v.y * v.y) + v.z * v.z) + v.w * v.w;
    #pragma unroll
    for (int off = 32; off >= 1; off >>= 1) s += __shfl_xor(s, off, 64);
    if ((tid & 63) == 0) zsq_g[blockIdx.x * 4 + (tid >> 6)] = s;
}

// ---------------- emb split (h+m) ----------------
__global__ __launch_bounds__(256)
void vq_split2_kernel(const float* __restrict__ src,
                      unsigned short* __restrict__ H,
                      unsigned short* __restrict__ M) {
    const size_t i = (size_t)blockIdx.x * 256 + threadIdx.x;
    float4 v = *(const float4*)&src[4 * i];
    ushort4 h, m;
    #define SP1(c) { h.c = f2bf(v.c); float r = v.c - bf2f(h.c); m.c = f2bf(r); }
    SP1(x) SP1(y) SP1(z) SP1(w)
    #undef SP1
    *(ushort4*)&H[4 * i] = h;
    *(ushort4*)&M[4 * i] = m;
}

// ---------------- MFMA GEMM v4: R5 dataflow, 8-wave block ----------------
// (verified R7 — unchanged)
__global__ __launch_bounds__(512, 2)
void vq_gemm_kernel(const unsigned short* __restrict__ Zh,
                    const unsigned short* __restrict__ Zm,
                    const unsigned short* __restrict__ Eh,
                    const unsigned short* __restrict__ Em,
                    const float* __restrict__ zsq_g,
                    const float* __restrict__ esq_g,
                    int* __restrict__ top2) {
    __shared__ __align__(16) unsigned short Albs[8 * 64 * 64];   // 64 KB
    __shared__ __align__(16) unsigned short Bbuf[2 * 256 * 64];  // 64 KB
    __shared__ float zsq_s[64];
    __shared__ float mvv[2][4][64][2];
    __shared__ int   mii[2][4][64][2];

    const int tid  = threadIdx.x;
    const int wid  = tid >> 6;        // 0..7
    const int lane = tid & 63;
    const int m0   = blockIdx.x * 64;
    const int rowL = lane & 15;
    const int kc   = lane >> 4;       // 0..3
    const int wm   = wid >> 2;        // row half: rows 32*wm..32*wm+31
    const int wn   = wid & 3;         // code quarter within a 256-code tile

    if (tid < 64) zsq_s[tid] = zsq_g[m0 + tid];

    // ---- persistent A stage: regions 0-3 = Zh kkb 0-3, 4-7 = Zm kkb 0-3 ----
    {
        const int slot = lane & 7;
        #pragma unroll
        for (int i = 0; i < 8; ++i) {
            const int rowlin = wid * 64 + i * 8 + (lane >> 3);   // 0..511
            const int region = rowlin >> 6;
            const int r      = rowlin & 63;
            const int c      = slot ^ (r & 7);
            const unsigned short* Ap = (region < 4) ? Zh : Zm;
            const int kkb = region & 3;
            GLL16(Ap + (size_t)(m0 + r) * DIM + kkb * 64 + c * 8,
                  (char*)Albs + wid * 8192 + i * 1024);
        }
    }

    // ---- B tile stage: 256 codes x 64 d (32 KB); 4 GLL16 per thread ----
    auto stage_b = [&](int nt_, int s_, int buf_) {
        const unsigned short* Bp = (s_ < 4) ? Eh : Em;
        const int kkb  = s_ & 3;
        const int slot = lane & 7;
        #pragma unroll
        for (int i = 0; i < 4; ++i) {
            const int chunk = wid * 4 + i;                       // 0..31
            const int codelin = chunk * 8 + (lane >> 3);         // 0..255
            const int c = slot ^ (codelin & 7);
            GLL16(Bp + (size_t)(nt_ * 256 + codelin) * DIM + kkb * 64 + c * 8,
                  (char*)Bbuf + buf_ * 32768 + chunk * 1024);
        }
    };

    stage_b(0, 0, 0);
    __syncthreads();

    float b1v[8], b2v[8];
    int   b1i[8], b2i[8];
    #pragma unroll
    for (int e = 0; e < 8; ++e) {
        b1v[e] = FLT_MAX; b2v[e] = FLT_MAX;
        b1i[e] = 0x7fffffff; b2i[e] = 0x7fffffff;
    }

    #pragma unroll 1
    for (int nt = 0; nt < 8; ++nt) {
        f32x4 acc[2][4];
        #pragma unroll
        for (int mf = 0; mf < 2; ++mf)
            #pragma unroll
            for (int nf = 0; nf < 4; ++nf)
                acc[mf][nf] = (f32x4){0.f, 0.f, 0.f, 0.f};

        #pragma unroll
        for (int s = 0; s < 8; ++s) {
            const int cb = s & 1;
            // prefetch next step into the other buffer
            {
                const int sn  = (s + 1) & 7;
                const int ntn = (s == 7) ? nt + 1 : nt;
                if (ntn < 8) stage_b(ntn, sn, cb ^ 1);
            }
            const int kkb = s & 3;
            // B fragments (LDS): codes wn*64 .. wn*64+63 of this tile
            short8 bF[4][2];
            #pragma unroll
            for (int nf = 0; nf < 4; ++nf) {
                const int ct = wn * 64 + nf * 16 + rowL;         // 0..255
                #pragma unroll
                for (int kh = 0; kh < 2; ++kh) {
                    const int sw = (kh * 4 + kc) ^ (ct & 7);
                    bF[nf][kh] = *(const short8*)((const char*)Bbuf + cb * 32768 + ct * 128 + sw * 16);
                }
            }
            // A-plane passes: s<4 (Eh): Zh then Zm; s>=4 (Em): Zh only
            const int NPL = (s < 4) ? 2 : 1;
            #pragma unroll
            for (int pl = 0; pl < NPL; ++pl) {
                const int region = (pl == 0 ? 0 : 4) + kkb;
                short8 aF[2][2];
                #pragma unroll
                for (int mf = 0; mf < 2; ++mf)
                    #pragma unroll
                    for (int kh = 0; kh < 2; ++kh) {
                        const int r = wm * 32 + mf * 16 + rowL;  // 0..63
                        const int sw = (kh * 4 + kc) ^ (r & 7);
                        aF[mf][kh] = *(const short8*)((const char*)Albs + region * 8192 + r * 128 + sw * 16);
                    }
                #pragma unroll
                for (int kh = 0; kh < 2; ++kh)
                    #pragma unroll
                    for (int mf = 0; mf < 2; ++mf)
                        #pragma unroll
                        for (int nf = 0; nf < 4; ++nf)
                            acc[mf][nf] = __builtin_amdgcn_mfma_f32_16x16x32_bf16(
                                aF[mf][kh], bF[nf][kh], acc[mf][nf], 0, 0, 0);
            }
            __syncthreads();
        }

        // ---- score this nt: dist = fl(zs+es) - 2*cross, running top-2 ----
        #pragma unroll
        for (int nf = 0; nf < 4; ++nf) {
            const int code = nt * 256 + wn * 64 + nf * 16 + rowL;
            const float es = esq_g[code];
            #pragma unroll
            for (int mf = 0; mf < 2; ++mf)
                #pragma unroll
                for (int rg = 0; rg < 4; ++rg) {
                    const int e = mf * 4 + rg;
                    const float zs = zsq_s[wm * 32 + mf * 16 + kc * 4 + rg];
                    float t = zs + es;
                    float dist = t - 2.0f * acc[mf][nf][rg];
                    bool better1 = (dist < b1v[e]) || (dist == b1v[e] && code < b1i[e]);
                    float ov = b1v[e]; int oi = b1i[e];
                    if (better1) { b1v[e] = dist; b1i[e] = code; }
                    float dv = better1 ? ov : dist;
                    int   di = better1 ? oi : code;
                    bool ins2 = (dv < b2v[e]) || (dv == b2v[e] && di < b2i[e]);
                    if (ins2) { b2v[e] = dv; b2i[e] = di; }
                }
        }

        // ---- half boundary (nt 3 / 7): merge wave-local top2 across cols ----
        if ((nt & 3) == 3) {
            const int h = nt >> 2;
            #pragma unroll
            for (int e = 0; e < 8; ++e) {
                #pragma unroll
                for (int off = 1; off <= 8; off <<= 1) {
                    float o1v = __shfl_xor(b1v[e], off, 64); int o1i = __shfl_xor(b1i[e], off, 64);
                    float o2v = __shfl_xor(b2v[e], off, 64); int o2i = __shfl_xor(b2i[e], off, 64);
                    bool t1 = (o1v < b1v[e]) || (o1v == b1v[e] && o1i < b1i[e]);
                    float dv = t1 ? b1v[e] : o1v; int di = t1 ? b1i[e] : o1i;
                    if (t1) { b1v[e] = o1v; b1i[e] = o1i; }
                    bool t2 = (dv < b2v[e]) || (dv == b2v[e] && di < b2i[e]);
                    if (t2) { b2v[e] = dv; b2i[e] = di; }
                    bool t3 = (o2v < b2v[e]) || (o2v == b2v[e] && o2i < b2i[e]);
                    if (t3) { b2v[e] = o2v; b2i[e] = o2i; }
                }
            }
            if ((lane & 15) == 0) {
                #pragma unroll
                for (int mf = 0; mf < 2; ++mf)
                    #pragma unroll
                    for (int rg = 0; rg < 4; ++rg) {
                        const int rl = wm * 32 + mf * 16 + kc * 4 + rg;
                        const int e = mf * 4 + rg;
                        mvv[h][wn][rl][0] = b1v[e]; mii[h][wn][rl][0] = b1i[e];
                        mvv[h][wn][rl][1] = b2v[e]; mii[h][wn][rl][1] = b2i[e];
                    }
            }
            #pragma unroll
            for (int e = 0; e < 8; ++e) {
                b1v[e] = FLT_MAX; b2v[e] = FLT_MAX;
                b1i[e] = 0x7fffffff; b2i[e] = 0x7fffffff;
            }
        }
    }

    __syncthreads();
    // ---- final merge across the 4 code-quarters, write top-2 per half ----
    if (tid < 128) {
        const int h = tid >> 6, r = tid & 63;
        float v1 = FLT_MAX, v2 = FLT_MAX;
        int i1 = 0x7fffffff, i2 = 0x7fffffff;
        #pragma unroll
        for (int w = 0; w < 4; ++w)
            #pragma unroll
            for (int e2 = 0; e2 < 2; ++e2) {
                float v = mvv[h][w][r][e2]; int ii = mii[h][w][r][e2];
                bool t1 = (v < v1) || (v == v1 && ii < i1);
                if (t1) { v2 = v1; i2 = i1; v1 = v; i1 = ii; }
                else {
                    bool t2 = (v < v2) || (v == v2 && ii < i2);
                    if (t2) { v2 = v; i2 = ii; }
                }
            }
        top2[(m0 + r) * 4 + h * 2 + 0] = i1;
        top2[(m0 + r) * 4 + h * 2 + 1] = i2;
    }
}

// ---------------- exact rescore v2: cooperative 16-lane dot ----------------
// R8 vs R7: the old rescue had all 64 lanes compute a FULL 256-d serial
// dot for candidate (lane&3) -> 16x duplicated compute + a 256-long
// dependent fmaf chain (577 us, VALUBusy 6.7%). Now group g (16 lanes)
// owns candidate g; lane l covers dims {64j+4l..+3}; tree-reduce within
// the group, lexicographic (dist,idx) min across groups. 8 float4 loads
// + 16 fmaf per lane. Rescore rounding changes (tree vs chain) but
// candidate gaps O(1) >> fp32 error O(1e-4).
__global__ __launch_bounds__(256)
void vq_rescue_kernel(const float* __restrict__ z, const float* __restrict__ emb,
                      const float* __restrict__ zsq_g, const float* __restrict__ esq_g,
                      const int* __restrict__ top2,
                      float* __restrict__ out, float* __restrict__ loss_acc) {
    __shared__ float lred[4];
    const int tid = threadIdx.x;
    const int wid = tid >> 6, lane = tid & 63;
    const int row = blockIdx.x * 4 + wid;
    const int g = lane >> 4;          // candidate group 0..3
    const int l = lane & 15;          // lane within group
    const int cand = top2[row * 4 + g];
    const float* zr = z + (size_t)row * DIM;
    const float* er = emb + (size_t)cand * DIM;

    float a = 0.f;
    #pragma unroll
    for (int j = 0; j < 4; ++j) {
        float4 zv = *(const float4*)&zr[j * 64 + 4 * l];
        float4 ev = *(const float4*)&er[j * 64 + 4 * l];
        a = fmaf(zv.x, ev.x, a); a = fmaf(zv.y, ev.y, a);
        a = fmaf(zv.z, ev.z, a); a = fmaf(zv.w, ev.w, a);
    }
    // tree-reduce dot within the 16-lane group
    #pragma unroll
    for (int off = 1; off <= 8; off <<= 1) a += __shfl_xor(a, off, 64);
    float dist = (zsq_g[row] + esq_g[cand]) - 2.0f * a;
    int best = cand;
    // lexicographic min across the 4 groups
    #pragma unroll
    for (int off = 16; off <= 32; off <<= 1) {
        float ov = __shfl_xor(dist, off, 64);
        int   oi = __shfl_xor(best, off, 64);
        bool tk = (ov < dist) || (ov == dist && oi < best);
        dist = tk ? ov : dist; best = tk ? oi : best;
    }

    // epilogue: z_q_st, loss partial, index (unchanged arithmetic)
    float4 q4 = *(const float4*)&emb[(size_t)best * DIM + 4 * lane];
    float4 z4 = *(const float4*)&zr[4 * lane];
    float4 o; float dx, lsum = 0.f;
    dx = q4.x - z4.x; o.x = z4.x + dx; lsum = fmaf(dx, dx, lsum);
    dx = q4.y - z4.y; o.y = z4.y + dx; lsum = fmaf(dx, dx, lsum);
    dx = q4.z - z4.z; o.z = z4.z + dx; lsum = fmaf(dx, dx, lsum);
    dx = q4.w - z4.w; o.w = z4.w + dx; lsum = fmaf(dx, dx, lsum);
    *(float4*)&out[(size_t)row * DIM + 4 * lane] = o;
    #pragma unroll
    for (int off = 32; off >= 1; off >>= 1) lsum += __shfl_xor(lsum, off, 64);
    if (lane == 0) lred[wid] = lsum;
    __syncthreads();
    if (tid == 0) atomicAdd(loss_acc, lred[0] + lred[1] + lred[2] + lred[3]);
    if (lane == 0) out[(size_t)N_ROWS * DIM + 1 + row] = (float)best;
}

// =================== legacy R2 path (fallback if ws too small) ===========
#define MT 128
#define KT 256
#define DC 16
#define BLOCK 256
#define ZSTR (MT + 4)
#define ESTR (KT + 4)
#define NSTAGES ((DIM / DC) * (K_CODES / KT))

#define LOHALF(v) __builtin_shufflevector(v, v, 0, 1)
#define HIHALF(v) __builtin_shufflevector(v, v, 2, 3)
#define PK_FMA_LO(acc, ap, bp) \
    asm("v_pk_fma_f32 %0, %1, %2, %0 op_sel:[0,0,0] op_sel_hi:[0,1,1]" \
        : "+v"(acc) : "v"(ap), "v"(bp))
#define PK_FMA_HI(acc, ap, bp) \
    asm("v_pk_fma_f32 %0, %1, %2, %0 op_sel:[1,0,0] op_sel_hi:[1,1,1]" \
        : "+v"(acc) : "v"(ap), "v"(bp))

__global__ __launch_bounds__(BLOCK, 1)
void vq_main_kernel(const float* __restrict__ z,
                    const float* __restrict__ emb,
                    const float* __restrict__ esq,
                    float* __restrict__ out,
                    float* __restrict__ loss_acc) {
    __shared__ float zS[2][DC][ZSTR];
    __shared__ float eT[2][DC][ESTR];
    __shared__ float zsq_s[MT];
    __shared__ int   best_s[MT];
    __shared__ float lred[4];

    const int tid = threadIdx.x;
    const int m0  = blockIdx.x * MT;
    const int rg  = tid >> 5;
    const int cg  = tid & 31;
    const int esr = tid >> 2;
    const int esf = tid & 3;
    const int zr  = tid >> 1;
    const int zh  = tid & 1;

    {
        const float* zp = &z[(size_t)(m0 + zr) * DIM + zh * 64];
        float sA = 0.f, sB = 0.f;
        #pragma unroll
        for (int d4 = 0; d4 < 16; ++d4) {
            float4 v = *(const float4*)&zp[d4 * 4];
            sA += v.x * v.x; sA += v.y * v.y; sA += v.z * v.z; sA += v.w * v.w;
        }
        #pragma unroll
        for (int d4 = 0; d4 < 16; ++d4) {
            float4 v = *(const float4*)&zp[128 + d4 * 4];
            sB += v.x * v.x; sB += v.y * v.y; sB += v.z * v.z; sB += v.w * v.w;
        }
        float s = sA + sB;
        s += __shfl_down(s, 1, 64);
        if (zh == 0) zsq_s[zr] = s;
    }
    {
        const float* zp = &z[(size_t)(m0 + zr) * DIM + 8 * zh];
        float4 za = *(const float4*)&zp[0];
        float4 zb = *(const float4*)&zp[4];
        zS[0][8 * zh + 0][zr] = za.x; zS[0][8 * zh + 1][zr] = za.y;
        zS[0][8 * zh + 2][zr] = za.z; zS[0][8 * zh + 3][zr] = za.w;
        zS[0][8 * zh + 4][zr] = zb.x; zS[0][8 * zh + 5][zr] = zb.y;
        zS[0][8 * zh + 6][zr] = zb.z; zS[0][8 * zh + 7][zr] = zb.w;
        #pragma unroll
        for (int cb = 0; cb < 4; ++cb) {
            int c = esr + cb * 64;
            float4 ev = *(const float4*)&emb[(size_t)c * DIM + 4 * esf];
            eT[0][4 * esf + 0][c] = ev.x; eT[0][4 * esf + 1][c] = ev.y;
            eT[0][4 * esf + 2][c] = ev.z; eT[0][4 * esf + 3][c] = ev.w;
        }
    }
    __syncthreads();

    float bestv[16];
    int   besti[16];
    #pragma unroll
    for (int j = 0; j < 16; ++j) { bestv[j] = FLT_MAX; besti[j] = 0; }

    f32x2 acc2[16][4];

    for (int s = 0; s < NSTAGES; ++s) {
        const int p     = s & 1;
        const int kt    = (s >> 4) * KT;
        const int dcIdx = s & 15;

        if (dcIdx == 0) {
            #pragma unroll
            for (int j = 0; j < 16; ++j)
                #pragma unroll
                for (int i2 = 0; i2 < 4; ++i2) acc2[j][i2] = (f32x2){0.f, 0.f};
        }

        const int sn  = (s + 1 < NSTAGES) ? s + 1 : s;
        const int nkt = (sn >> 4) * KT;
        const int ndc = (sn & 15) * DC;
        float4 zn0 = *(const float4*)&z[(size_t)(m0 + zr) * DIM + ndc + 8 * zh];
        float4 zn1 = *(const float4*)&z[(size_t)(m0 + zr) * DIM + ndc + 8 * zh + 4];
        float4 en0 = *(const float4*)&emb[(size_t)(nkt + esr +   0) * DIM + ndc + 4 * esf];
        float4 en1 = *(const float4*)&emb[(size_t)(nkt + esr +  64) * DIM + ndc + 4 * esf];
        float4 en2 = *(const float4*)&emb[(size_t)(nkt + esr + 128) * DIM + ndc + 4 * esf];
        float4 en3 = *(const float4*)&emb[(size_t)(nkt + esr + 192) * DIM + ndc + 4 * esf];

        #pragma unroll
        for (int d = 0; d < DC; ++d) {
            f32x4 a0 = *(const f32x4*)&zS[p][d][16 * rg];
            f32x4 a1 = *(const f32x4*)&zS[p][d][16 * rg + 4];
            f32x4 a2 = *(const f32x4*)&zS[p][d][16 * rg + 8];
            f32x4 a3 = *(const f32x4*)&zS[p][d][16 * rg + 12];
            f32x4 b0 = *(const f32x4*)&eT[p][d][4 * cg];
            f32x4 b1 = *(const f32x4*)&eT[p][d][128 + 4 * cg];
            f32x2 ap[8] = { LOHALF(a0), HIHALF(a0), LOHALF(a1), HIHALF(a1),
                            LOHALF(a2), HIHALF(a2), LOHALF(a3), HIHALF(a3) };
            f32x2 bp[4] = { LOHALF(b0), HIHALF(b0), LOHALF(b1), HIHALF(b1) };
            #pragma unroll
            for (int jp = 0; jp < 8; ++jp) {
                #pragma unroll
                for (int i2 = 0; i2 < 4; ++i2) {
                    PK_FMA_LO(acc2[2 * jp][i2],     ap[jp], bp[i2]);
                    PK_FMA_HI(acc2[2 * jp + 1][i2], ap[jp], bp[i2]);
                }
            }
        }
        {
            const int q = p ^ 1;
            zS[q][8 * zh + 0][zr] = zn0.x; zS[q][8 * zh + 1][zr] = zn0.y;
            zS[q][8 * zh + 2][zr] = zn0.z; zS[q][8 * zh + 3][zr] = zn0.w;
            zS[q][8 * zh + 4][zr] = zn1.x; zS[q][8 * zh + 5][zr] = zn1.y;
            zS[q][8 * zh + 6][zr] = zn1.z; zS[q][8 * zh + 7][zr] = zn1.w;
            eT[q][4 * esf + 0][esr      ] = en0.x; eT[q][4 * esf + 1][esr      ] = en0.y;
            eT[q][4 * esf + 2][esr      ] = en0.z; eT[q][4 * esf + 3][esr      ] = en0.w;
            eT[q][4 * esf + 0][esr +  64] = en1.x; eT[q][4 * esf + 1][esr +  64] = en1.y;
            eT[q][4 * esf + 2][esr +  64] = en1.z; eT[q][4 * esf + 3][esr +  64] = en1.w;
            eT[q][4 * esf + 0][esr + 128] = en2.x; eT[q][4 * esf + 1][esr + 128] = en2.y;
            eT[q][4 * esf + 2][esr + 128] = en2.z; eT[q][4 * esf + 3][esr + 128] = en2.w;
            eT[q][4 * esf + 0][esr + 192] = en3.x; eT[q][4 * esf + 1][esr + 192] = en3.y;
            eT[q][4 * esf + 2][esr + 192] = en3.z; eT[q][4 * esf + 3][esr + 192] = en3.w;
        }
        if (dcIdx == 15) {
            float4 e0 = *(const float4*)&esq[kt + 4 * cg];
            float4 e1 = *(const float4*)&esq[kt + 128 + 4 * cg];
            float es[8] = {e0.x, e0.y, e0.z, e0.w, e1.x, e1.y, e1.z, e1.w};
            #pragma unroll
            for (int j = 0; j < 16; ++j) {
                float zs = zsq_s[16 * rg + j];
                #pragma unroll
                for (int i = 0; i < 8; ++i) {
                    float aij  = acc2[j][i >> 1][i & 1];
                    float t    = zs + es[i];
                    float dist = t - 2.0f * aij;
                    int idx = (i < 4) ? (kt + 4 * cg + i) : (kt + 128 + 4 * cg + (i - 4));
                    bool better = (dist < bestv[j]);
                    bestv[j] = better ? dist : bestv[j];
                    besti[j] = better ? idx  : besti[j];
                }
            }
        }
        __syncthreads();
    }

    #pragma unroll
    for (int off = 16; off >= 1; off >>= 1) {
        #pragma unroll
        for (int j = 0; j < 16; ++j) {
            float ov = __shfl_xor(bestv[j], off, 64);
            int   oi = __shfl_xor(besti[j], off, 64);
            bool take = (ov < bestv[j]) || (ov == bestv[j] && oi < besti[j]);
            bestv[j] = take ? ov : bestv[j];
            besti[j] = take ? oi : besti[j];
        }
    }
    if (cg == 0) {
        #pragma unroll
        for (int j = 0; j < 16; ++j) best_s[16 * rg + j] = besti[j];
    }
    __syncthreads();

    float lsum = 0.f;
    const int d4 = tid & 63;
    for (int it = 0; it < 32; ++it) {
        int r  = (tid >> 6) + it * 4;
        int bk = best_s[r];
        float4 q4 = *(const float4*)&emb[(size_t)bk * DIM + 4 * d4];
        float4 z4 = *(const float4*)&z[(size_t)(m0 + r) * DIM + 4 * d4];
        float4 o;
        float dx;
        dx = q4.x - z4.x; o.x = z4.x + dx; lsum = fmaf(dx, dx, lsum);
        dx = q4.y - z4.y; o.y = z4.y + dx; lsum = fmaf(dx, dx, lsum);
        dx = q4.z - z4.z; o.z = z4.z + dx; lsum = fmaf(dx, dx, lsum);
        dx = q4.w - z4.w; o.w = z4.w + dx; lsum = fmaf(dx, dx, lsum);
        *(float4*)&out[(size_t)(m0 + r) * DIM + 4 * d4] = o;
    }
    #pragma unroll
    for (int off = 32; off >= 1; off >>= 1) lsum += __shfl_xor(lsum, off, 64);
    if ((tid & 63) == 0) lred[tid >> 6] = lsum;
    __syncthreads();
    if (tid == 0) {
        float bs = lred[0] + lred[1] + lred[2] + lred[3];
        atomicAdd(loss_acc, bs);
    }
    if (tid < MT) out[(size_t)N_ROWS * DIM + 1 + m0 + tid] = (float)best_s[tid];
}

// ---------------- finalize: vq_loss = 1.25 * mean ----------------
__global__ void vq_finalize_kernel(const float* __restrict__ loss_acc,
                                   float* __restrict__ out) {
    double s = (double)loss_acc[0];
    out[(size_t)N_ROWS * DIM] = (float)(s * 1.25 / ((double)N_ROWS * (double)DIM));
}

extern "C" void kernel_launch(void* const* d_in, const int* in_sizes, int n_in,
                              void* d_out, int out_size, void* d_ws, size_t ws_size,
                              hipStream_t stream) {
    (void)in_sizes; (void)n_in; (void)out_size;
    const float* z   = (const float*)d_in[0];
    const float* emb = (const float*)d_in[1];
    float* out = (float*)d_out;
    char* wsb = (char*)d_ws;
    float* loss_acc = (float*)wsb;              // @0
    float* esq      = (float*)(wsb + 1024);     // 2048 f

    hipMemsetAsync(d_ws, 0, sizeof(float), stream);
    vq_esq_kernel<<<K_CODES / 4, 256, 0, stream>>>(emb, esq);

    const size_t NEED = (size_t)72 << 20;       // Zh/Zm end at 72 MiB
    if (ws_size >= NEED) {
        float* zsq_g = (float*)(wsb + 16384);              // 65536 f
        int*   top2  = (int*)(wsb + ((size_t)1 << 19));    // 65536*4 int
        unsigned short* Eh = (unsigned short*)(wsb + ((size_t)2 << 20));
        unsigned short* Em = (unsigned short*)(wsb + ((size_t)3 << 20));
        unsigned short* Zh = (unsigned short*)(wsb + ((size_t)8 << 20));
        unsigned short* Zm = (unsigned short*)(wsb + ((size_t)40 << 20));
        vq_splitz_kernel<<<(N_ROWS * DIM) / 1024, 256, 0, stream>>>(z, Zh, Zm, zsq_g);
        vq_split2_kernel<<<(K_CODES * DIM) / 1024, 256, 0, stream>>>(emb, Eh, Em);
        vq_gemm_kernel<<<N_ROWS / 64, 512, 0, stream>>>(Zh, Zm, Eh, Em,
                                                        zsq_g, esq, top2);
        vq_rescue_kernel<<<N_ROWS / 4, 256, 0, stream>>>(z, emb, zsq_g, esq, top2,
                                                         out, loss_acc);
    } else {
        vq_main_kernel<<<N_ROWS / MT, BLOCK, 0, stream>>>(z, emb, esq, out, loss_acc);
    }
    vq_finalize_kernel<<<1, 1, 0, stream>>>(loss_acc, out);
}